// Round 9
// baseline (486.932 us; speedup 1.0000x reference)
//
#include <hip/hip_runtime.h>
#include <stdint.h>

#define NROWS 16384
#define QNUM  8192
#define ED    512
#define BM    128
#define BN    128
#define KTILES 8           // K tiles of 64 elements
#define QBLKS  (QNUM / BN) // 64
#define DELTA  0.04f       // fp8 ranking-error margin (>=6 sigma even for RTZ cvt)
#define ESLOT  17          // 16 top2-entries per row + 1 pad (uint4 units) — R7-exact

typedef long  l2    __attribute__((ext_vector_type(2)));   // 16 B = two i64 fp8x8 fragments
typedef float f32x4 __attribute__((ext_vector_type(4)));

// keep top-2 (smallest val, tie -> smallest idx), branchless
static __device__ __forceinline__ void ins2(float& v1, int& q1, float& v2, int& q2,
                                            float s, int q) {
    const bool b1 = (s < v1) || (s == v1 && q < q1);
    const bool b2 = (s < v2) || (s == v2 && q < q2);
    const float nv2 = b1 ? v1 : (b2 ? s : v2);
    const int   nq2 = b1 ? q1 : (b2 ? q : q2);
    v1 = b1 ? s : v1;
    q1 = b1 ? q : q1;
    v2 = nv2; q2 = nq2;
}

// sorted top-3 insert (v1<=v2<=v3 invariant, tie -> smaller idx)
static __device__ __forceinline__ void ins3(float& v1, int& q1, float& v2, int& q2,
                                            float& v3, int& q3, float s, int q) {
    const bool b1 = (s < v1) || (s == v1 && q < q1);
    const bool b2 = (s < v2) || (s == v2 && q < q2);
    const bool b3 = (s < v3) || (s == v3 && q < q3);
    const float nv3 = b2 ? v2 : (b3 ? s : v3);
    const int   nq3 = b2 ? q2 : (b3 ? q : q3);
    const float nv2 = b1 ? v1 : (b2 ? s : v2);
    const int   nq2 = b1 ? q1 : (b2 ? q : q2);
    v1 = b1 ? s : v1; q1 = b1 ? q : q1;
    v2 = nv2; q2 = nq2; v3 = nv3; q3 = nq3;
}

// ---------------- prep: fp32 -> fp8 e4m3 (HW cvt) into MFMA-fragment-tiled layout ----------------
// Pair-chunk (rt, kt) = rows rt*16..+15 x K kt*64..+63 = 1 KB. Lane l=g*16+c owns
// 16 B: low 8 B = A[row rt*16+c][kt*64 + g*8 ..+8], high 8 B = same +32 — exactly
// the two fp8 16x16x32 MFMA fragments, so each K-loop load is one contiguous
// wave-wide 1 KB burst (half the bytes/lines of the bf16 R7 path).
// scale: w is subnormal in e4m3 (sigma 0.001) -> scale by 2^9 (lossless), epilogue
// rescales by 2^-9.
__global__ __launch_bounds__(256) void k_prep_fp8(const float* __restrict__ src,
                                                  unsigned long long* __restrict__ dst,
                                                  float scale) {
    size_t u = (size_t)blockIdx.x * 256 + threadIdx.x;   // one 8-elem group per thread
    const float4* p = (const float4*)(src + u * 8);
    float4 a = p[0], b = p[1];
    int lo = __builtin_amdgcn_cvt_pk_fp8_f32(a.x * scale, a.y * scale, 0, false);
    lo     = __builtin_amdgcn_cvt_pk_fp8_f32(a.z * scale, a.w * scale, lo, true);
    int hi = __builtin_amdgcn_cvt_pk_fp8_f32(b.x * scale, b.y * scale, 0, false);
    hi     = __builtin_amdgcn_cvt_pk_fp8_f32(b.z * scale, b.w * scale, hi, true);
    const unsigned long long v = (unsigned)lo | ((unsigned long long)(unsigned)hi << 32);
    const int r = (int)(u >> 6), kk = (int)(u & 63);     // 64 groups per row
    const int kt = kk >> 3, rem = kk & 7;
    const int g = rem & 3, half = rem >> 2;
    const int rt = r >> 4, c = r & 15;
    dst[((size_t)(rt * 8 + kt) * 64 + g * 16 + c) * 2 + half] = v;
}

// ---------------- numpy-pairwise fp32 sum of squares per 512-row (unchanged) ----------------
#define SROWS 32
#define SSTRIDE 520
__global__ __launch_bounds__(256) void k_sumsq_np(const float* __restrict__ src,
                                                  float* __restrict__ dst) {
    __shared__ float ld[SROWS * SSTRIDE];
    const int t = threadIdx.x;
    const size_t base = (size_t)blockIdx.x * SROWS * ED;
    #pragma unroll
    for (int k = 0; k < 16; ++k) {
        int u = k * 256 + t;
        int row = u >> 7;
        int c4  = u & 127;
        float4 v = ((const float4*)(src + base))[u];
        float* d = ld + row * SSTRIDE + c4 * 4;
        d[0] = v.x; d[1] = v.y; d[2] = v.z; d[3] = v.w;
    }
    __syncthreads();
    const int row = t >> 3, j = t & 7;
    const float* a = ld + row * SSTRIDE;
    float B[4];
    #pragma unroll
    for (int b = 0; b < 4; ++b) {
        const float* p = a + b * 128 + j;
        float r = __fmul_rn(p[0], p[0]);
        #pragma unroll
        for (int i = 1; i < 16; ++i) {
            float q = p[8 * i];
            r = __fadd_rn(r, __fmul_rn(q, q));
        }
        float t1 = __fadd_rn(r,  __shfl_xor(r,  1, 64));
        float t2 = __fadd_rn(t1, __shfl_xor(t1, 2, 64));
        B[b]     = __fadd_rn(t2, __shfl_xor(t2, 4, 64));
    }
    if (j == 0)
        dst[(size_t)blockIdx.x * SROWS + row] =
            __fadd_rn(__fadd_rn(B[0], B[1]), __fadd_rn(B[2], B[3]));
}

// ---------------- phase 1: fp8 MFMA (bf16 rate, half the memory) + R7-exact epilogue ----------------
// R8's xor-4/ESLOT-9 epilogue caused replay-dependent index flips (unproven
// mechanism) -> reverted to the R7 epilogue verbatim (xor-8 only, 16 entries,
// ESLOT 17). This round's change is the orthogonal fp8 format switch, plus a
// top-3 (instead of top-2) final merge to absorb fp8 ranking noise.
__global__ __launch_bounds__(256, 2) void k_gemm_top2(
        const l2* __restrict__ xb,    // fragment-tiled fp8
        const l2* __restrict__ wb,    // fragment-tiled fp8 (x512)
        const float* __restrict__ wsqf,
        uint2* __restrict__ p3a, uint2* __restrict__ p3b, uint2* __restrict__ p3c) {
    __shared__ uint4 ered[BM * ESLOT];   // 34,816 B (R7-exact)

    const int t  = threadIdx.x;
    const int wv = t >> 6;
    const int l  = t & 63;
    const int c  = l & 15;   // MFMA col / A-row lane
    const int g  = l >> 4;   // MFMA quad
    const int RB = (wv >> 1) * 64;
    const int CB = (wv & 1) * 64;

    // XCD-aware swizzle (R6+): id%8 = XCD; each XCD keeps 8 q-panels L2-hot.
    const int id = blockIdx.x;
    const int qb = (id & 7) * 8 + ((id >> 3) & 7);  // 0..63
    const int rb = id >> 6;                          // 0..127
    const int q0 = qb * BN;
    const int r0 = rb * BM;

    f32x4 acc[4][4];
    #pragma unroll
    for (int i = 0; i < 4; ++i)
        #pragma unroll
        for (int j = 0; j < 4; ++j)
            acc[i][j] = (f32x4){0.f, 0.f, 0.f, 0.f};

    const l2* ga = xb + ((size_t)((r0 + RB) >> 4) * 8) * 64 + l;
    const l2* gb = wb + ((size_t)((q0 + CB) >> 4) * 8) * 64 + l;

    l2 Af[2][4], Bf[2][4];   // [buf][tile] — 16 B per frag-pair (two K-32 fragments)

    #pragma unroll
    for (int i = 0; i < 4; ++i) Af[0][i] = ga[(size_t)(i * 8) * 64];
    #pragma unroll
    for (int j = 0; j < 4; ++j) Bf[0][j] = gb[(size_t)(j * 8) * 64];

    #pragma unroll
    for (int kt = 0; kt < KTILES; ++kt) {
        const int cur = kt & 1, nxt = cur ^ 1;
        if (kt + 1 < KTILES) {   // depth-1 prefetch: next tile in flight across MFMAs
            #pragma unroll
            for (int i = 0; i < 4; ++i) Af[nxt][i] = ga[(size_t)(i * 8 + kt + 1) * 64];
            #pragma unroll
            for (int j = 0; j < 4; ++j) Bf[nxt][j] = gb[(size_t)(j * 8 + kt + 1) * 64];
        }
        #pragma unroll
        for (int s = 0; s < 2; ++s)
            #pragma unroll
            for (int i = 0; i < 4; ++i)
                #pragma unroll
                for (int j = 0; j < 4; ++j) {
                    const long a8 = s ? Af[cur][i].y : Af[cur][i].x;
                    const long b8 = s ? Bf[cur][j].y : Bf[cur][j].x;
                    acc[i][j] = __builtin_amdgcn_mfma_f32_16x16x32_fp8_fp8(a8, b8, acc[i][j], 0, 0, 0);
                }
    }

    // epilogue — R7-exact structure; score = wsq - 2*dot*2^-9 (w was scaled by 2^9)
    float wsqv[4];
    #pragma unroll
    for (int j = 0; j < 4; ++j) wsqv[j] = wsqf[q0 + CB + j * 16 + c];

    #pragma unroll
    for (int i = 0; i < 4; ++i) {
        #pragma unroll
        for (int r = 0; r < 4; ++r) {
            float bv1 = 3.4e38f, bv2 = 3.4e38f;
            int   bq1 = 0x7fffffff, bq2 = 0x7fffffff;
            #pragma unroll
            for (int j = 0; j < 4; ++j) {
                const float s = fmaf(-0.00390625f, acc[i][j][r], wsqv[j]);  // -2/512
                const int   q = q0 + CB + j * 16 + c;
                ins2(bv1, bq1, bv2, bq2, s, q);
            }
            // single xor-8 merge: lanes c and c^8 end identical; c<8 writes
            {
                float ov1 = __shfl_xor(bv1, 8, 64);
                int   oq1 = __shfl_xor(bq1, 8, 64);
                float ov2 = __shfl_xor(bv2, 8, 64);
                int   oq2 = __shfl_xor(bq2, 8, 64);
                ins2(bv1, bq1, bv2, bq2, ov1, oq1);
                ins2(bv1, bq1, bv2, bq2, ov2, oq2);
            }
            if (c < 8) {
                const int row = RB + i * 16 + g * 4 + r;
                ered[row * ESLOT + (wv & 1) * 8 + c] =
                    make_uint4(__float_as_uint(bv1), (unsigned)bq1,
                               __float_as_uint(bv2), (unsigned)bq2);
            }
        }
    }
    __syncthreads();
    if (t < BM) {
        const uint4* e = &ered[t * ESLOT];
        float v1 = 3.4e38f, v2 = 3.4e38f, v3 = 3.4e38f;
        int   q1 = 0x7fffffff, q2 = 0x7fffffff, q3 = 0x7fffffff;
        #pragma unroll
        for (int k = 0; k < 16; ++k) {
            const uint4 E = e[k];
            ins3(v1, q1, v2, q2, v3, q3, __uint_as_float(E.x), (int)E.y);
            ins3(v1, q1, v2, q2, v3, q3, __uint_as_float(E.z), (int)E.w);
        }
        const size_t o = (size_t)(r0 + t) * QBLKS + qb;
        p3a[o] = make_uint2(__float_as_uint(v1), (unsigned)q1);
        p3b[o] = make_uint2(__float_as_uint(v2), (unsigned)q2);
        p3c[o] = make_uint2(__float_as_uint(v3), (unsigned)q3);
    }
}

// ---------------- phase 2: fp32-emulated (numpy semantics) rescore + gather ----------------
__global__ __launch_bounds__(256) void k_rescore(
        const uint2* __restrict__ p3a,
        const uint2* __restrict__ p3b,
        const uint2* __restrict__ p3c,
        const float* __restrict__ x,
        const float* __restrict__ wt,
        const float* __restrict__ wsqf,
        const float* __restrict__ xsqf,
        float* __restrict__ outq,
        float* __restrict__ outi) {
    const int wv = threadIdx.x >> 6, l = threadIdx.x & 63;
    const int row = blockIdx.x * 4 + wv;
    const size_t o = (size_t)row * QBLKS + l;

    const uint2 e0 = p3a[o], e1 = p3b[o], e2 = p3c[o];
    float vv[3] = { __uint_as_float(e0.x), __uint_as_float(e1.x), __uint_as_float(e2.x) };
    int   qq[3] = { (int)e0.y, (int)e1.y, (int)e2.y };

    float gm = vv[0];
    #pragma unroll
    for (int m = 1; m < 64; m <<= 1) gm = fminf(gm, __shfl_xor(gm, m, 64));
    const float thr = gm + DELTA;

    const float4* xp = (const float4*)(x + (size_t)row * ED + l * 8);
    const float4 xa = xp[0], xbv = xp[1];
    const float xsq = xsqf[row];

    float bestv = 3.4e38f; int bestq = 0x7fffffff;
    #pragma unroll
    for (int k = 0; k < 3; ++k) {
        unsigned long long mm = __ballot(vv[k] <= thr);
        while (mm) {
            const int ln = __ffsll(mm) - 1;
            mm &= mm - 1;
            const int q = __shfl(qq[k], ln, 64);
            const float4* wp = (const float4*)(wt + (size_t)q * ED + l * 8);
            const float4 wa = wp[0], wbv = wp[1];
            double d = (double)xa.x * wa.x + (double)xa.y * wa.y
                     + (double)xa.z * wa.z + (double)xa.w * wa.w
                     + (double)xbv.x * wbv.x + (double)xbv.y * wbv.y
                     + (double)xbv.z * wbv.z + (double)xbv.w * wbv.w;
            #pragma unroll
            for (int m = 1; m < 64; m <<= 1) d += __shfl_xor(d, m, 64);
            // numpy fp32 semantics: fl32( fl32(x_sq - 2*dot) + w_sq ), first-occurrence argmin
            const float dotf = (float)d;
            const float t1 = __fadd_rn(xsq, __fmul_rn(-2.0f, dotf));
            const float sc = __fadd_rn(t1, wsqf[q]);
            if (sc < bestv || (sc == bestv && q < bestq)) { bestv = sc; bestq = q; }
        }
    }
    const float4* wp = (const float4*)(wt + (size_t)bestq * ED + l * 8);
    float4* op = (float4*)(outq + (size_t)row * ED + l * 8);
    op[0] = wp[0]; op[1] = wp[1];
    if (l == 0) outi[row] = (float)bestq;
}

extern "C" void kernel_launch(void* const* d_in, const int* in_sizes, int n_in,
                              void* d_out, int out_size, void* d_ws, size_t ws_size,
                              hipStream_t stream) {
    (void)in_sizes; (void)n_in; (void)out_size; (void)ws_size;
    const float* x  = (const float*)d_in[0];
    const float* wt = (const float*)d_in[1];

    char* ws = (char*)d_ws;
    unsigned long long* xb8 = (unsigned long long*)ws;               //  8,388,608 B
    unsigned long long* wb8 = (unsigned long long*)(ws + 8388608);   //  4,194,304 B
    float* wsqf = (float*)(ws + 12582912);                           //     32,768 B
    float* xsqf = (float*)(ws + 12615680);                           //     65,536 B
    uint2* p3a  = (uint2*)(ws + 12681216);                           //  8,388,608 B
    uint2* p3b  = (uint2*)(ws + 21069824);                           //  8,388,608 B
    uint2* p3c  = (uint2*)(ws + 29458432);                           //  8,388,608 B (end 37.8 MB)

    float* outq = (float*)d_out;
    float* outi = outq + (size_t)NROWS * ED;

    k_prep_fp8<<<4096, 256, 0, stream>>>(x,  xb8, 1.0f);
    k_prep_fp8<<<2048, 256, 0, stream>>>(wt, wb8, 512.0f);   // 2^9: lifts w out of e4m3 subnormals
    k_sumsq_np<<<NROWS / SROWS, 256, 0, stream>>>(x,  xsqf);
    k_sumsq_np<<<QNUM  / SROWS, 256, 0, stream>>>(wt, wsqf);
    k_gemm_top2<<<8192, 256, 0, stream>>>((const l2*)xb8, (const l2*)wb8, wsqf, p3a, p3b, p3c);
    k_rescore<<<4096, 256, 0, stream>>>(p3a, p3b, p3c, x, wt, wsqf, xsqf, outq, outi);
}

// Round 10
// 242.094 us; speedup vs baseline: 2.0113x; 2.0113x over previous
//
#include <hip/hip_runtime.h>
#include <stdint.h>

#define NROWS 16384
#define QNUM  8192
#define ED    512
#define BM    128
#define BN    128
#define KTILES 8           // K tiles of 64 elements
#define QBLKS  (QNUM / BN) // 64
#define DELTA  0.02f       // >=6 sigma of (err_i - err_j) for fp8 ranking noise
#define ESLOT  17          // 16 top2-key entries per row + 1 pad (uint2 units)

typedef long  l2    __attribute__((ext_vector_type(2)));   // 16 B = two i64 fp8x8 fragments
typedef float f32x4 __attribute__((ext_vector_type(4)));

// sortable key: monotone float->uint, low 13 bits replaced by q index (0..8191).
// score perturbation from clearing 13 mantissa bits <= ~6e-5 at |s|~0.1 — absorbed
// by DELTA. min-key == (min score, tie -> min idx).
static __device__ __forceinline__ unsigned enc_key(float s, unsigned idx) {
    const unsigned b = __float_as_uint(s);
    const unsigned m = (unsigned)(((int)b) >> 31) | 0x80000000u;
    return ((b ^ m) & 0xFFFFE000u) | idx;
}
// decode key -> floored float value (<= true score)
static __device__ __forceinline__ float dec_key(unsigned k) {
    const unsigned u = k & 0xFFFFE000u;
    return (u & 0x80000000u) ? __uint_as_float(u ^ 0x80000000u)
                             : __uint_as_float(~u);
}

static __device__ __forceinline__ void ins3k(unsigned& v1, unsigned& v2, unsigned& v3,
                                             unsigned k) {
    const bool b1 = k < v1, b2 = k < v2, b3 = k < v3;
    v3 = b2 ? v2 : (b3 ? k : v3);
    v2 = b1 ? v1 : (b2 ? k : v2);
    v1 = b1 ? k : v1;
}

// ---------------- fused prep: numpy-pairwise sumsq + fp32->fp8 fragment-tiled ----------------
// Sumsq phase is the R2-verified numpy-pairwise tree, verbatim. fp8 phase converts
// the same LDS slab into the R9 fragment-tiled granule layout (byte-identical
// mapping: granule kk of row r -> dst[((rt*8+kt)*64 + g*16 + c)*2 + half]).
#define SROWS 32
#define SSTRIDE 520
__global__ __launch_bounds__(256) void k_prep_sumsq(const float* __restrict__ src,
                                                    float* __restrict__ dst_sq,
                                                    unsigned long long* __restrict__ dst8,
                                                    float scale) {
    __shared__ float ld[SROWS * SSTRIDE];
    const int t = threadIdx.x;
    const size_t base = (size_t)blockIdx.x * SROWS * ED;
    #pragma unroll
    for (int k = 0; k < 16; ++k) {
        int u = k * 256 + t;
        int row = u >> 7;
        int c4  = u & 127;
        float4 v = ((const float4*)(src + base))[u];
        float* d = ld + row * SSTRIDE + c4 * 4;
        d[0] = v.x; d[1] = v.y; d[2] = v.z; d[3] = v.w;
    }
    __syncthreads();
    const int row = t >> 3, j = t & 7;
    const float* a = ld + row * SSTRIDE;
    float B[4];
    #pragma unroll
    for (int b = 0; b < 4; ++b) {
        const float* p = a + b * 128 + j;
        float r = __fmul_rn(p[0], p[0]);
        #pragma unroll
        for (int i = 1; i < 16; ++i) {
            float q = p[8 * i];
            r = __fadd_rn(r, __fmul_rn(q, q));
        }
        float t1 = __fadd_rn(r,  __shfl_xor(r,  1, 64));
        float t2 = __fadd_rn(t1, __shfl_xor(t1, 2, 64));
        B[b]     = __fadd_rn(t2, __shfl_xor(t2, 4, 64));
    }
    if (j == 0)
        dst_sq[(size_t)blockIdx.x * SROWS + row] =
            __fadd_rn(__fadd_rn(B[0], B[1]), __fadd_rn(B[2], B[3]));

    // fp8 phase: thread (row, j) converts granules kk = j*8 + gi (gi 0..7)
    const int gr = blockIdx.x * SROWS + row;        // global row
    const int rt = gr >> 4, cc = gr & 15;
    #pragma unroll
    for (int gi = 0; gi < 8; ++gi) {
        const float* e = a + (j * 8 + gi) * 8;      // 8 consecutive elems
        int lo = __builtin_amdgcn_cvt_pk_fp8_f32(e[0] * scale, e[1] * scale, 0, false);
        lo     = __builtin_amdgcn_cvt_pk_fp8_f32(e[2] * scale, e[3] * scale, lo, true);
        int hi = __builtin_amdgcn_cvt_pk_fp8_f32(e[4] * scale, e[5] * scale, 0, false);
        hi     = __builtin_amdgcn_cvt_pk_fp8_f32(e[6] * scale, e[7] * scale, hi, true);
        const unsigned long long v = (unsigned)lo | ((unsigned long long)(unsigned)hi << 32);
        const int g = gi & 3, half = gi >> 2;       // kt = j
        dst8[((size_t)(rt * 8 + j) * 64 + g * 16 + cc) * 2 + half] = v;
    }
}

// ---------------- phase 1: fp8 MFMA + sortable-key top-2 epilogue ----------------
// K-loop identical to R9 (control). Epilogue: same skeleton (per-(i,r) local
// top-2, single xor-8 merge, c<8 LDS write, final per-row scan) but payload is
// one uint32 key instead of (float,int) pairs -> ~650 fewer VALU instrs/wave,
// half the shuffle words, ered 34.8 -> 17.4 KB.
__global__ __launch_bounds__(256, 2) void k_gemm_top2(
        const l2* __restrict__ xb,    // fragment-tiled fp8
        const l2* __restrict__ wb,    // fragment-tiled fp8 (x512)
        const float* __restrict__ wsqf,
        uint4* __restrict__ p3) {
    __shared__ uint2 ered[BM * ESLOT];   // 17,408 B

    const int t  = threadIdx.x;
    const int wv = t >> 6;
    const int l  = t & 63;
    const int c  = l & 15;   // MFMA col / A-row lane
    const int g  = l >> 4;   // MFMA quad
    const int RB = (wv >> 1) * 64;
    const int CB = (wv & 1) * 64;

    // XCD-aware swizzle (R6+): id%8 = XCD; each XCD keeps 8 q-panels L2-hot.
    const int id = blockIdx.x;
    const int qb = (id & 7) * 8 + ((id >> 3) & 7);  // 0..63
    const int rb = id >> 6;                          // 0..127
    const int q0 = qb * BN;
    const int r0 = rb * BM;

    f32x4 acc[4][4];
    #pragma unroll
    for (int i = 0; i < 4; ++i)
        #pragma unroll
        for (int j = 0; j < 4; ++j)
            acc[i][j] = (f32x4){0.f, 0.f, 0.f, 0.f};

    const l2* ga = xb + ((size_t)((r0 + RB) >> 4) * 8) * 64 + l;
    const l2* gb = wb + ((size_t)((q0 + CB) >> 4) * 8) * 64 + l;

    l2 Af[2][4], Bf[2][4];   // [buf][tile]

    #pragma unroll
    for (int i = 0; i < 4; ++i) Af[0][i] = ga[(size_t)(i * 8) * 64];
    #pragma unroll
    for (int j = 0; j < 4; ++j) Bf[0][j] = gb[(size_t)(j * 8) * 64];

    #pragma unroll
    for (int kt = 0; kt < KTILES; ++kt) {
        const int cur = kt & 1, nxt = cur ^ 1;
        if (kt + 1 < KTILES) {   // depth-1 prefetch: next tile in flight across MFMAs
            #pragma unroll
            for (int i = 0; i < 4; ++i) Af[nxt][i] = ga[(size_t)(i * 8 + kt + 1) * 64];
            #pragma unroll
            for (int j = 0; j < 4; ++j) Bf[nxt][j] = gb[(size_t)(j * 8 + kt + 1) * 64];
        }
        #pragma unroll
        for (int s = 0; s < 2; ++s)
            #pragma unroll
            for (int i = 0; i < 4; ++i)
                #pragma unroll
                for (int j = 0; j < 4; ++j) {
                    const long a8 = s ? Af[cur][i].y : Af[cur][i].x;
                    const long b8 = s ? Bf[cur][j].y : Bf[cur][j].x;
                    acc[i][j] = __builtin_amdgcn_mfma_f32_16x16x32_fp8_fp8(a8, b8, acc[i][j], 0, 0, 0);
                }
    }

    // epilogue: score = wsq - 2*dot*2^-9 (w scaled by 2^9 at prep)
    float wsqv[4]; unsigned kidx[4];
    #pragma unroll
    for (int j = 0; j < 4; ++j) {
        const int qj = q0 + CB + j * 16 + c;
        wsqv[j] = wsqf[qj];
        kidx[j] = (unsigned)qj;
    }

    #pragma unroll
    for (int i = 0; i < 4; ++i) {
        #pragma unroll
        for (int r = 0; r < 4; ++r) {
            unsigned k0 = enc_key(fmaf(-0.00390625f, acc[i][0][r], wsqv[0]), kidx[0]);
            unsigned k1 = enc_key(fmaf(-0.00390625f, acc[i][1][r], wsqv[1]), kidx[1]);
            unsigned k2 = enc_key(fmaf(-0.00390625f, acc[i][2][r], wsqv[2]), kidx[2]);
            unsigned k3 = enc_key(fmaf(-0.00390625f, acc[i][3][r], wsqv[3]), kidx[3]);
            // top-2 of 4 (keys are distinct: idx embedded)
            const unsigned a01 = min(k0, k1), b01 = max(k0, k1);
            const unsigned a23 = min(k2, k3), b23 = max(k2, k3);
            unsigned v1 = min(a01, a23);
            unsigned v2 = min(min(max(a01, a23), b01), b23);
            // single xor-8 merge of two disjoint 8-col groups
            const unsigned o1 = __shfl_xor((int)v1, 8, 64);
            const unsigned o2 = __shfl_xor((int)v2, 8, 64);
            const unsigned nv1 = min(v1, o1);
            v2 = min(min(max(v1, o1), v2), o2);
            v1 = nv1;
            if (c < 8) {
                const int row = RB + i * 16 + g * 4 + r;
                ered[row * ESLOT + (wv & 1) * 8 + c] = make_uint2(v1, v2);
            }
        }
    }
    __syncthreads();
    if (t < BM) {
        const uint2* e = &ered[t * ESLOT];
        unsigned v1 = 0xFFFFFFFFu, v2 = 0xFFFFFFFFu, v3 = 0xFFFFFFFFu;
        #pragma unroll
        for (int k = 0; k < 16; ++k) {
            const uint2 E = e[k];
            ins3k(v1, v2, v3, E.x);
            ins3k(v1, v2, v3, E.y);
        }
        p3[(size_t)(r0 + t) * QBLKS + qb] = make_uint4(v1, v2, v3, 0xFFFFFFFFu);
    }
}

// ---------------- phase 2: fp32-emulated (numpy semantics) rescore + gather ----------------
__global__ __launch_bounds__(256) void k_rescore(
        const uint4* __restrict__ p3,
        const float* __restrict__ x,
        const float* __restrict__ wt,
        const float* __restrict__ wsqf,
        const float* __restrict__ xsqf,
        float* __restrict__ outq,
        float* __restrict__ outi) {
    const int wv = threadIdx.x >> 6, l = threadIdx.x & 63;
    const int row = blockIdx.x * 4 + wv;

    const uint4 P = p3[(size_t)row * QBLKS + l];
    unsigned vk[3] = { P.x, P.y, P.z };

    unsigned gk = vk[0];
    #pragma unroll
    for (int m = 1; m < 64; m <<= 1) gk = min(gk, (unsigned)__shfl_xor((int)gk, m, 64));
    // threshold in key space: decode floored gm, add DELTA, re-encode, idx bits = 1s
    const float tf = dec_key(gk) + DELTA;
    const unsigned tb = __float_as_uint(tf);
    const unsigned tm = (unsigned)(((int)tb) >> 31) | 0x80000000u;
    const unsigned thrkey = (tb ^ tm) | 0x1FFFu;

    const float4* xp = (const float4*)(x + (size_t)row * ED + l * 8);
    const float4 xa = xp[0], xbv = xp[1];
    const float xsq = xsqf[row];

    float bestv = 3.4e38f; int bestq = 0x7fffffff;
    #pragma unroll
    for (int k = 0; k < 3; ++k) {
        unsigned long long mm = __ballot(vk[k] <= thrkey);
        while (mm) {
            const int ln = __ffsll(mm) - 1;
            mm &= mm - 1;
            const int q = __shfl((int)vk[k], ln, 64) & 0x1FFF;
            const float4* wp = (const float4*)(wt + (size_t)q * ED + l * 8);
            const float4 wa = wp[0], wbv = wp[1];
            double d = (double)xa.x * wa.x + (double)xa.y * wa.y
                     + (double)xa.z * wa.z + (double)xa.w * wa.w
                     + (double)xbv.x * wbv.x + (double)xbv.y * wbv.y
                     + (double)xbv.z * wbv.z + (double)xbv.w * wbv.w;
            #pragma unroll
            for (int m = 1; m < 64; m <<= 1) d += __shfl_xor(d, m, 64);
            // numpy fp32 semantics: fl32( fl32(x_sq - 2*dot) + w_sq ), first-occurrence argmin
            const float dotf = (float)d;
            const float t1 = __fadd_rn(xsq, __fmul_rn(-2.0f, dotf));
            const float sc = __fadd_rn(t1, wsqf[q]);
            if (sc < bestv || (sc == bestv && q < bestq)) { bestv = sc; bestq = q; }
        }
    }
    const float4* wp = (const float4*)(wt + (size_t)bestq * ED + l * 8);
    float4* op = (float4*)(outq + (size_t)row * ED + l * 8);
    op[0] = wp[0]; op[1] = wp[1];
    if (l == 0) outi[row] = (float)bestq;
}

extern "C" void kernel_launch(void* const* d_in, const int* in_sizes, int n_in,
                              void* d_out, int out_size, void* d_ws, size_t ws_size,
                              hipStream_t stream) {
    (void)in_sizes; (void)n_in; (void)out_size; (void)ws_size;
    const float* x  = (const float*)d_in[0];
    const float* wt = (const float*)d_in[1];

    char* ws = (char*)d_ws;
    unsigned long long* xb8 = (unsigned long long*)ws;               //  8,388,608 B
    unsigned long long* wb8 = (unsigned long long*)(ws + 8388608);   //  4,194,304 B
    float* wsqf = (float*)(ws + 12582912);                           //     32,768 B
    float* xsqf = (float*)(ws + 12615680);                           //     65,536 B
    uint4* p3   = (uint4*)(ws + 12681216);                           // 16,777,216 B (end ~29.5 MB)

    float* outq = (float*)d_out;
    float* outi = outq + (size_t)NROWS * ED;

    k_prep_sumsq<<<NROWS / SROWS, 256, 0, stream>>>(x,  xsqf, xb8, 1.0f);
    k_prep_sumsq<<<QNUM  / SROWS, 256, 0, stream>>>(wt, wsqf, wb8, 512.0f);  // 2^9 lifts w out of e4m3 subnormals
    k_gemm_top2<<<8192, 256, 0, stream>>>((const l2*)xb8, (const l2*)wb8, wsqf, p3);
    k_rescore<<<4096, 256, 0, stream>>>(p3, x, wt, wsqf, xsqf, outq, outi);
}